// Round 6
// baseline (1661.632 us; speedup 1.0000x reference)
//
#include <hip/hip_runtime.h>
#include <math.h>

#define BB 1024
#define CC 64
#define HH 32
#define VV 4096
#define NEL (BB*CC*HH)   // 2097152

#define RT 128        // rows per argmin block
#define TV 64         // code tile in LDS (49.7KB total -> 3 blocks/CU)

// ---------------- setup ----------------

__device__ double dev_cubic(double x){
#pragma clang fp contract(off)
  const double A = -0.75;
  x = fabs(x);
  if (x <= 1.0) return ((A + 2.0)*x - (A + 3.0))*x*x + 1.0;
  if (x < 2.0)  return A*(((x - 5.0)*x + 8.0)*x - 4.0);
  return 0.0;
}

__device__ __constant__ int c_vpatch[10] = {1,2,3,4,6,9,13,18,24,32};
__device__ __constant__ int c_pref[10]   = {0,1,3,6,10,16,25,38,56,80};

__global__ void gen_setup(float* Mdown, float* Mup, double* partial){
#pragma clang fp contract(off)
  int t = threadIdx.x;
  for (int i = t; i < 3584; i += 64) { Mdown[i] = 0.0f; Mup[i] = 0.0f; }
  if (t < 16) partial[t] = 0.0;
  __syncthreads();
  if (t < 20) {
    int si = t >> 1; int up = t & 1;
    int pn = c_vpatch[si];
    if (!up) {
      float* M = Mdown + c_pref[si]*32;          // [pn][32], align_corners=True
      for (int o = 0; o < pn; o++){
        double src = (pn == 1) ? 0.0 : (double)(o*(32-1)) / (double)(pn-1);
        double fl = floor(src); double tt = src - fl; int fli = (int)fl;
        for (int k = -1; k <= 2; k++){
          int j = fli + k; j = j < 0 ? 0 : (j > 31 ? 31 : j);
          float w = (float)dev_cubic((double)k - tt);
          M[o*32 + j] = M[o*32 + j] + w;
        }
      }
    } else {
      float* M = Mup + c_pref[si]*32;            // [32][pn], align_corners=False
      for (int o = 0; o < 32; o++){
        double src = ((double)o + 0.5) * (double)pn / 32.0 - 0.5;
        double fl = floor(src); double tt = src - fl; int fli = (int)fl;
        for (int k = -1; k <= 2; k++){
          int j = fli + k; j = j < 0 ? 0 : (j > pn-1 ? pn-1 : j);
          float w = (float)dev_cubic((double)k - tt);
          M[o*pn + j] = M[o*pn + j] + w;
        }
      }
    }
  }
}

// pack Phi center-column weights: wPack[pi][co*196 + ci*3 + kh] = w[pi][co][ci][kh][1]
__global__ void pack_w(const float* __restrict__ w, float* __restrict__ wPack){
  for (int e = blockIdx.x*blockDim.x + threadIdx.x; e < 4*64*196; e += gridDim.x*blockDim.x){
    int pi = e / (64*196);
    int r  = e - pi*64*196;
    int co = r / 196, m = r - co*196;
    float v = 0.0f;
    if (m < 192){
      int ci = m / 3, kh = m - ci*3;
      v = w[(((pi*64 + co)*64 + ci)*3 + kh)*3 + 1];
    }
    wPack[e] = v;
  }
}

// numpy scalar pairwise-8 sum of fl32 squares of 64 contiguous floats
__device__ float np_pairwise8_sq64(const float* a){
#pragma clang fp contract(off)
  float r0 = a[0]*a[0], r1 = a[1]*a[1], r2 = a[2]*a[2], r3 = a[3]*a[3];
  float r4 = a[4]*a[4], r5 = a[5]*a[5], r6 = a[6]*a[6], r7 = a[7]*a[7];
  for (int i = 8; i < 64; i += 8){
    float s0 = a[i+0]*a[i+0]; r0 = r0 + s0;
    float s1 = a[i+1]*a[i+1]; r1 = r1 + s1;
    float s2 = a[i+2]*a[i+2]; r2 = r2 + s2;
    float s3 = a[i+3]*a[i+3]; r3 = r3 + s3;
    float s4 = a[i+4]*a[i+4]; r4 = r4 + s4;
    float s5 = a[i+5]*a[i+5]; r5 = r5 + s5;
    float s6 = a[i+6]*a[i+6]; r6 = r6 + s6;
    float s7 = a[i+7]*a[i+7]; r7 = r7 + s7;
  }
  return ((r0 + r1) + (r2 + r3)) + ((r4 + r5) + (r6 + r7));
}

// e32T[c][v] = emb[v][c]; e_sq = pairwise8 norms
__global__ void prep_emb(const float* emb, float* e32T, float* e_sq){
  int v = blockIdx.x*blockDim.x + threadIdx.x;
  if (v >= VV) return;
  float row[64];
  for (int c = 0; c < CC; c++){
    float x = emb[v*CC + c];
    row[c] = x;
    e32T[c*VV + v] = x;
  }
  e_sq[v] = np_pairwise8_sq64(row);
}

// init: frest=f, fhat=0, rest0 = downsample(f) at scale 0 (pn=1)
__global__ __launch_bounds__(256) void init_k(const float* __restrict__ f,
    float* frest, float* fhat, float* rest0, const float* Md0){
#pragma clang fp contract(off)
  __shared__ float frL[64][33];
  __shared__ float m0[32];
  int b = blockIdx.x, t = threadIdx.x;
  if (t < 32) m0[t] = Md0[t];
  for (int e = t; e < 2048; e += 256){
    int c = e >> 5, h = e & 31;
    float v = f[b*2048 + e];
    frL[c][h] = v;
    frest[b*2048 + e] = v;
    fhat[b*2048 + e] = 0.0f;
  }
  __syncthreads();
  if (t < 64){
    float s = 0.0f;
    for (int h = 0; h < 32; h++){ float pr = m0[h]*frL[t][h]; s = s + pr; }
    rest0[b*64 + t] = s;
  }
}

// ---------------- argmin: 128 rows x vspl codes per block, 8x8 per thread ----------------

__global__ __launch_bounds__(256, 3) void argmin_k(const float* __restrict__ rest,
    const float* __restrict__ e32T, const float* __restrict__ e_sq,
    float* bestW, int* idxW, int pn, int vspl, int nsplit){
#pragma clang fp contract(off)
  __shared__ float rT[64][RT];   // [c][row] 32KB
  __shared__ float eL[64][TV];   // [c][code] 16KB
  __shared__ float sR[RT];
  int n0 = blockIdx.x * RT;
  int split = blockIdx.y;
  int v0 = split * vspl;
  int t = threadIdx.x;

  for (int e = t; e < RT*64; e += 256){
    int j = e & (RT-1), c = e >> 7;
    int n = n0 + j; int b = n / pn, p = n % pn;
    rT[c][j] = rest[(b*CC + c)*pn + p];
  }
  __syncthreads();
  if (t < RT){
#pragma clang fp contract(off)
    float r0 = rT[0][t]*rT[0][t], r1 = rT[1][t]*rT[1][t];
    float r2 = rT[2][t]*rT[2][t], r3 = rT[3][t]*rT[3][t];
    float r4 = rT[4][t]*rT[4][t], r5 = rT[5][t]*rT[5][t];
    float r6 = rT[6][t]*rT[6][t], r7 = rT[7][t]*rT[7][t];
    for (int i = 8; i < 64; i += 8){
      float s0 = rT[i+0][t]*rT[i+0][t]; r0 = r0 + s0;
      float s1 = rT[i+1][t]*rT[i+1][t]; r1 = r1 + s1;
      float s2 = rT[i+2][t]*rT[i+2][t]; r2 = r2 + s2;
      float s3 = rT[i+3][t]*rT[i+3][t]; r3 = r3 + s3;
      float s4 = rT[i+4][t]*rT[i+4][t]; r4 = r4 + s4;
      float s5 = rT[i+5][t]*rT[i+5][t]; r5 = r5 + s5;
      float s6 = rT[i+6][t]*rT[i+6][t]; r6 = r6 + s6;
      float s7 = rT[i+7][t]*rT[i+7][t]; r7 = r7 + s7;
    }
    sR[t] = ((r0 + r1) + (r2 + r3)) + ((r4 + r5) + (r6 + r7));
  }
  __syncthreads();

  int rg = t >> 4;   // owns rows rg*8..rg*8+7
  int cg = t & 15;   // owns codes cg*8.. within a TV=128-would-be... here cg<8 used twice? no:
  // TV=64: 16 cg groups x 8 codes = 128 > 64 -> use cg*4? Keep 8x8 but only 8 cg groups?
  // Instead: cg in 0..7 selects codes, duplicate factor 2 handled by rg covering 16 groups of 8 rows = 128 rows. 256 threads = 16 rg x 16 cg, but TV=64 has only 8 chunks of 8.
  // Resolution: per-thread tile 8 rows x 4 codes. cg*4 within TV=64.
  float sRl[8];
#pragma unroll
  for (int k2 = 0; k2 < 8; k2++) sRl[k2] = sR[rg*8 + k2];

  float best[8]; int bidx[8];
#pragma unroll
  for (int k2 = 0; k2 < 8; k2++){ best[k2] = 3.0e38f; bidx[k2] = 0; }

  int ntiles = vspl / TV;
  for (int tile = 0; tile < ntiles; tile++){
    int vt = v0 + tile*TV;
    for (int e = t; e < (64*TV)/4; e += 256){
      int c = e >> 4;          // 16 float4 per c-row
      int v4 = e & 15;
      *(float4*)&eL[c][v4*4] = *(const float4*)&e32T[c*VV + vt + v4*4];
    }
    __syncthreads();

    float acc[8][4];
#pragma unroll
    for (int a = 0; a < 8; a++)
#pragma unroll
      for (int k = 0; k < 4; k++) acc[a][k] = 0.0f;

    for (int c = 0; c < 64; c++){
      float4 ra = *(const float4*)&rT[c][rg*8];
      float4 rb = *(const float4*)&rT[c][rg*8 + 4];
      float4 ea = *(const float4*)&eL[c][cg*4];
      float rr[8] = {ra.x, ra.y, ra.z, ra.w, rb.x, rb.y, rb.z, rb.w};
      float ee[4] = {ea.x, ea.y, ea.z, ea.w};
#pragma unroll
      for (int a = 0; a < 8; a++)
#pragma unroll
        for (int k = 0; k < 4; k++)
          acc[a][k] = fmaf(ee[k], rr[a], acc[a][k]);   // c-ascending, single accumulator
    }

#pragma unroll
    for (int k2 = 0; k2 < 8; k2++){
#pragma unroll
      for (int k = 0; k < 4; k++){
        float es = e_sq[vt + cg*4 + k];
        float t1 = sRl[k2] + es;                        // fl(R + e_sq)
        float d  = t1 - 2.0f*acc[k2][k];                // fl(t1 - 2*dot)
        if (d < best[k2]) { best[k2] = d; bidx[k2] = vt + cg*4 + k; }
      }
    }
    __syncthreads();
  }

  // reduce per row over the 16 cg lanes of group rg
#pragma unroll
  for (int k2 = 0; k2 < 8; k2++){
    float v = best[k2]; int ix = bidx[k2];
    for (int off = 8; off; off >>= 1){
      float ov = __shfl_down(v, off, 16);
      int   oi = __shfl_down(ix, off, 16);
      if (ov < v || (ov == v && oi < ix)) { v = ov; ix = oi; }
    }
    if (cg == 0){
      int n = n0 + rg*8 + k2;
      bestW[n*nsplit + split] = v;
      idxW [n*nsplit + split] = ix;
    }
  }
}

__global__ void argmin_reduce(const float* bestW, const int* idxW, int* idx, int N, int nsplit){
  int n = blockIdx.x*blockDim.x + threadIdx.x;
  if (n >= N) return;
  float v = bestW[n*nsplit]; int ix = idxW[n*nsplit];
  for (int s = 1; s < nsplit; s++){
    float ov = bestW[n*nsplit + s];
    if (ov < v) { v = ov; ix = idxW[n*nsplit + s]; }   // strict <, splits ascending: first-min
  }
  idx[n] = ix;
}

// ---------------- fused upsample/gather + Phi + next-scale downsample ----------------

__global__ __launch_bounds__(256) void fused_phi(
    const float* __restrict__ emb, const int* __restrict__ idx,
    const float* __restrict__ Mup, const float* __restrict__ wP,
    const float* __restrict__ bias, const float* __restrict__ f,
    float* fhat, float* frest, float* levels_out, float* final_out,
    float* rest_next, const float* __restrict__ Mdown_next,
    double* partial, int si, int pn, int pn2, int is_last)
{
#pragma clang fp contract(off)
  __shared__ float huL[64][33];
  __shared__ union { float hE[24*64]; float frL[64*33]; } u;   // phase-disjoint
  __shared__ float wL[64*196];    // [co][ci*3+kh], stride 196 (float4-clean, 2-way banks)
  __shared__ float mUp[32*25];    // [o][p], stride pn+1
  __shared__ float mDn[32*33];    // [p][h], stride 33
  __shared__ int idxL[32];
  __shared__ double red[4];
  int b = blockIdx.x, t = threadIdx.x;

  if (t < pn) idxL[t] = idx[b*pn + t];
  // coalesced float4 staging of packed weights (12544 floats = 3136 float4)
  for (int e = t; e < 3136; e += 256)
    *(float4*)&wL[e*4] = *(const float4*)&wP[e*4];
  if (pn2 > 0){
    for (int e = t; e < pn2*32; e += 256){
      int p = e >> 5, h = e & 31;
      mDn[p*33 + h] = Mdown_next[e];
    }
  }
  if (!is_last){
    for (int e = t; e < 32*pn; e += 256){
      int o = e / pn, p = e - o*pn;
      mUp[o*(pn+1) + p] = Mup[e];
    }
  }
  __syncthreads();

  if (!is_last){
    for (int e = t; e < pn*64; e += 256){
      int p = e >> 6, c = e & 63;
      u.hE[p*64 + c] = emb[idxL[p]*64 + c];
    }
    __syncthreads();
    for (int e = t; e < 2048; e += 256){
      int c = e >> 5, o = e & 31;
      const float* mr = &mUp[o*(pn+1)];
      float s = 0.0f;
      for (int p = 0; p < pn; p++){ float pr = mr[p]*u.hE[p*64 + c]; s = s + pr; }
      huL[c][o] = s;
    }
  } else {
    for (int e = t; e < 2048; e += 256){
      int h = e >> 6, c = e & 63;
      huL[c][h] = emb[idxL[h]*64 + c];
    }
  }
  __syncthreads();   // hE dead after this point

  int co = t >> 2, h0 = (t & 3) * 8;
  float y[8];
#pragma unroll
  for (int uu = 0; uu < 8; uu++) y[uu] = 0.0f;
  for (int ci = 0; ci < 64; ci++){
    float x[10];
#pragma unroll
    for (int uu = 0; uu < 10; uu++){
      int hh = h0 - 1 + uu;
      x[uu] = (hh < 0 || hh > 31) ? 0.0f : huL[ci][hh];
    }
    const float* wp = &wL[co*196 + ci*3];
    float w0 = wp[0], w1 = wp[1], w2 = wp[2];
#pragma unroll
    for (int uu = 0; uu < 8; uu++){
      y[uu] = fmaf(w0, x[uu],   y[uu]);
      y[uu] = fmaf(w1, x[uu+1], y[uu]);
      y[uu] = fmaf(w2, x[uu+2], y[uu]);
    }
  }

  float bb = bias[co];
  double lsum = 0.0;
  int base = b*2048 + co*32 + h0;
#pragma unroll
  for (int uu = 0; uu < 8; uu++){
    float yv = y[uu] + bb;
    float hp = 0.5f*huL[co][h0+uu] + 0.5f*yv;
    float fh = fhat[base+uu] + hp;
    fhat[base+uu] = fh;
    float fr = frest[base+uu] - hp;
    frest[base+uu] = fr;
    u.frL[co*33 + h0 + uu] = fr;
    float fv = f[base+uu];
    float dv = fh - fv;
    lsum += (double)dv*(double)dv;
    levels_out[base+uu] = fh;
    if (is_last) final_out[base+uu] = dv + fv;    // straight-through: fl(fl(fh-f)+f)
  }
  for (int off = 32; off; off >>= 1) lsum += __shfl_down(lsum, off);
  if ((t & 63) == 0) red[t >> 6] = lsum;
  __syncthreads();

  if (pn2 > 0){
    for (int e = t; e < 64*pn2; e += 256){
      int c = e / pn2, p = e - c*pn2;
      const float* mr = &mDn[p*33];
      float s = 0.0f;
      for (int h = 0; h < 32; h++){ float pr = mr[h]*u.frL[c*33 + h]; s = s + pr; }
      rest_next[(b*64 + c)*pn2 + p] = s;
    }
  }
  if (t == 0) atomicAdd(&partial[si], red[0] + red[1] + red[2] + red[3]);
}

__global__ void finalize(const double* partial, float* out_loss){
#pragma clang fp contract(off)
  float L = 0.0f;
  for (int si = 0; si < 10; si++){
    float m = (float)(partial[si] / (double)NEL);
    float t1 = 0.25f * m;
    L = L + t1;
    L = L + m;
  }
  L = L / 10.0f;
  *out_loss = L;
}

// ---------------- host ----------------

extern "C" void kernel_launch(void* const* d_in, const int* in_sizes, int n_in,
                              void* d_out, int out_size, void* d_ws, size_t ws_size,
                              hipStream_t stream) {
  const float* f     = (const float*)d_in[0];
  const float* emb   = (const float*)d_in[1];
  const float* phi_w = (const float*)d_in[2];
  const float* phi_b = (const float*)d_in[3];
  float* out0       = (float*)d_out;
  float* out_loss   = out0 + NEL;
  float* out_levels = out0 + NEL + 1;

  double* partial = (double*)d_ws;             // 16
  float*  e32T    = (float*)(partial + 16);    // 262144
  float*  e_sq    = e32T + 262144;             // 4096
  float*  frest   = e_sq + 4096;               // NEL
  float*  fhat    = frest + NEL;               // NEL
  float*  rest    = fhat + NEL;                // NEL (max)
  float*  Mdown   = rest + NEL;                // 3584
  float*  Mup     = Mdown + 3584;              // 3584
  float*  wPack   = Mup + 3584;                // 4*64*196 = 50176
  float*  bestW   = wPack + 50176;             // 262144 (max index N*nsplit <= 262144)
  int*    idxW    = (int*)(bestW + 262144);    // 262144
  int*    idxbuf  = idxW + 262144;             // 32768

  // pi table: exact IEEE-fp64 mirror of np.linspace + argmin(|TICKS - si/9|)
  double q = 1.0/3.0; q = q/4.0;
  double start = q;
  double stop  = 1.0 - q;
  double delta = stop - start;
  double step  = delta/3.0;
  double ticks[4];
  ticks[0] = start;
  ticks[1] = step + start;
  { double t2 = 2.0*step; ticks[2] = t2 + start; }
  ticks[3] = stop;
  int pi_tab[10];
  for (int si = 0; si < 10; si++){
    double x = (double)si / 9.0;
    int bi = 0; double bd = fabs(ticks[0] - x);
    for (int i2 = 1; i2 < 4; i2++){
      double dd = fabs(ticks[i2] - x);
      if (dd < bd) { bd = dd; bi = i2; }
    }
    pi_tab[si] = bi;
  }

  static const int vp[10]   = {1,2,3,4,6,9,13,18,24,32};
  static const int pref[10] = {0,1,3,6,10,16,25,38,56,80};

  gen_setup<<<1, 64, 0, stream>>>(Mdown, Mup, partial);
  pack_w<<<64, 256, 0, stream>>>(phi_w, wPack);
  prep_emb<<<16, 256, 0, stream>>>(emb, e32T, e_sq);
  init_k<<<BB, 256, 0, stream>>>(f, frest, fhat, rest, Mdown /* scale0: [1][32] */);

  for (int si = 0; si < 10; si++){
    int pn = vp[si];
    int N = BB*pn;
    int nsplit = (pn <= 4) ? 32 : ((pn <= 9) ? 16 : 8);
    int vspl = VV / nsplit;
    dim3 ag(N/RT, nsplit);
    // LAST SCALE quantizes f itself (reference: rest = f); f layout == rest layout at pn=32
    const float* restp = (si == 9) ? f : rest;
    argmin_k<<<ag, 256, 0, stream>>>(restp, e32T, e_sq, bestW, idxW, pn, vspl, nsplit);
    argmin_reduce<<<(N + 255)/256, 256, 0, stream>>>(bestW, idxW, idxbuf, N, nsplit);
    int pn2 = (si < 8) ? vp[si+1] : 0;   // scale 9 quantizes f, no downsample needed at si=8
    fused_phi<<<BB, 256, 0, stream>>>(emb, idxbuf, Mup + pref[si]*32,
        wPack + (size_t)pi_tab[si]*64*196, phi_b + (size_t)pi_tab[si]*CC,
        f, fhat, frest, out_levels + (size_t)si*NEL, out0,
        rest, (si < 8) ? (Mdown + pref[si+1]*32) : Mdown,
        partial, si, pn, pn2, si == 9 ? 1 : 0);
  }
  finalize<<<1, 1, 0, stream>>>(partial, out_loss);
}

// Round 7
// 1532.971 us; speedup vs baseline: 1.0839x; 1.0839x over previous
//
#include <hip/hip_runtime.h>
#include <math.h>

#define BB 1024
#define CC 64
#define HH 32
#define VV 4096
#define NEL (BB*CC*HH)   // 2097152

#define RT 128        // rows per argmin block
#define TV 64         // code tile in LDS

// ---------------- setup ----------------

__device__ double dev_cubic(double x){
#pragma clang fp contract(off)
  const double A = -0.75;
  x = fabs(x);
  if (x <= 1.0) return ((A + 2.0)*x - (A + 3.0))*x*x + 1.0;
  if (x < 2.0)  return A*(((x - 5.0)*x + 8.0)*x - 4.0);
  return 0.0;
}

__device__ __constant__ int c_vpatch[10] = {1,2,3,4,6,9,13,18,24,32};
__device__ __constant__ int c_pref[10]   = {0,1,3,6,10,16,25,38,56,80};

__global__ void gen_setup(float* Mdown, float* Mup, double* partial){
#pragma clang fp contract(off)
  int t = threadIdx.x;
  for (int i = t; i < 3584; i += 64) { Mdown[i] = 0.0f; Mup[i] = 0.0f; }
  if (t < 16) partial[t] = 0.0;
  __syncthreads();
  if (t < 20) {
    int si = t >> 1; int up = t & 1;
    int pn = c_vpatch[si];
    if (!up) {
      float* M = Mdown + c_pref[si]*32;          // [pn][32], align_corners=True
      for (int o = 0; o < pn; o++){
        double src = (pn == 1) ? 0.0 : (double)(o*(32-1)) / (double)(pn-1);
        double fl = floor(src); double tt = src - fl; int fli = (int)fl;
        for (int k = -1; k <= 2; k++){
          int j = fli + k; j = j < 0 ? 0 : (j > 31 ? 31 : j);
          float w = (float)dev_cubic((double)k - tt);
          M[o*32 + j] = M[o*32 + j] + w;
        }
      }
    } else {
      float* M = Mup + c_pref[si]*32;            // [32][pn], align_corners=False
      for (int o = 0; o < 32; o++){
        double src = ((double)o + 0.5) * (double)pn / 32.0 - 0.5;
        double fl = floor(src); double tt = src - fl; int fli = (int)fl;
        for (int k = -1; k <= 2; k++){
          int j = fli + k; j = j < 0 ? 0 : (j > pn-1 ? pn-1 : j);
          float w = (float)dev_cubic((double)k - tt);
          M[o*pn + j] = M[o*pn + j] + w;
        }
      }
    }
  }
}

// pack Phi center-column weights: wPack[pi][co*196 + ci*3 + kh] = w[pi][co][ci][kh][1]
__global__ void pack_w(const float* __restrict__ w, float* __restrict__ wPack){
  for (int e = blockIdx.x*blockDim.x + threadIdx.x; e < 4*64*196; e += gridDim.x*blockDim.x){
    int pi = e / (64*196);
    int r  = e - pi*64*196;
    int co = r / 196, m = r - co*196;
    float v = 0.0f;
    if (m < 192){
      int ci = m / 3, kh = m - ci*3;
      v = w[(((pi*64 + co)*64 + ci)*3 + kh)*3 + 1];
    }
    wPack[e] = v;
  }
}

// numpy scalar pairwise-8 sum of fl32 squares of 64 contiguous floats
__device__ float np_pairwise8_sq64(const float* a){
#pragma clang fp contract(off)
  float r0 = a[0]*a[0], r1 = a[1]*a[1], r2 = a[2]*a[2], r3 = a[3]*a[3];
  float r4 = a[4]*a[4], r5 = a[5]*a[5], r6 = a[6]*a[6], r7 = a[7]*a[7];
  for (int i = 8; i < 64; i += 8){
    float s0 = a[i+0]*a[i+0]; r0 = r0 + s0;
    float s1 = a[i+1]*a[i+1]; r1 = r1 + s1;
    float s2 = a[i+2]*a[i+2]; r2 = r2 + s2;
    float s3 = a[i+3]*a[i+3]; r3 = r3 + s3;
    float s4 = a[i+4]*a[i+4]; r4 = r4 + s4;
    float s5 = a[i+5]*a[i+5]; r5 = r5 + s5;
    float s6 = a[i+6]*a[i+6]; r6 = r6 + s6;
    float s7 = a[i+7]*a[i+7]; r7 = r7 + s7;
  }
  return ((r0 + r1) + (r2 + r3)) + ((r4 + r5) + (r6 + r7));
}

// e32T[c][v] = emb[v][c]; e_sq = pairwise8 norms
__global__ void prep_emb(const float* emb, float* e32T, float* e_sq){
  int v = blockIdx.x*blockDim.x + threadIdx.x;
  if (v >= VV) return;
  float row[64];
  for (int c = 0; c < CC; c++){
    float x = emb[v*CC + c];
    row[c] = x;
    e32T[c*VV + v] = x;
  }
  e_sq[v] = np_pairwise8_sq64(row);
}

// init: frest=f, fhat=0, rest0 = downsample(f) at scale 0 (pn=1)
__global__ __launch_bounds__(256) void init_k(const float* __restrict__ f,
    float* frest, float* fhat, float* rest0, const float* Md0){
#pragma clang fp contract(off)
  __shared__ float frL[64][33];
  __shared__ float m0[32];
  int b = blockIdx.x, t = threadIdx.x;
  if (t < 32) m0[t] = Md0[t];
  for (int e = t; e < 2048; e += 256){
    int c = e >> 5, h = e & 31;
    float v = f[b*2048 + e];
    frL[c][h] = v;
    frest[b*2048 + e] = v;
    fhat[b*2048 + e] = 0.0f;
  }
  __syncthreads();
  if (t < 64){
    float s = 0.0f;
    for (int h = 0; h < 32; h++){ float pr = m0[h]*frL[t][h]; s = s + pr; }
    rest0[b*64 + t] = s;
  }
}

// ---------------- argmin: 128 rows x VSPL codes per block, 8r x 4c per thread ----------------

template<int PN, int NSPLIT>
__global__ __launch_bounds__(256) void argmin_k(const float* __restrict__ rest,
    const float* __restrict__ e32T, const float* __restrict__ e_sq,
    float* bestW, int* idxW){
#pragma clang fp contract(off)
  constexpr int VSPL = VV / NSPLIT;
  constexpr int NT   = VSPL / TV;
  __shared__ float rT[64][RT];   // 32KB
  __shared__ float eL[64][TV];   // 16KB
  __shared__ float sR[RT];
  __shared__ float esL[VSPL];    // <=2KB
  int n0 = blockIdx.x * RT;
  int split = blockIdx.y;
  int v0 = split * VSPL;
  int t = threadIdx.x;

  for (int e = t; e < RT*64; e += 256){
    int j = e & (RT-1), c = e >> 7;
    int n = n0 + j; int b = n / PN, p = n % PN;   // compile-time divisor
    rT[c][j] = rest[(b*CC + c)*PN + p];
  }
  for (int e = t; e < VSPL; e += 256) esL[e] = e_sq[v0 + e];
  __syncthreads();
  if (t < RT){
#pragma clang fp contract(off)
    float r0 = rT[0][t]*rT[0][t], r1 = rT[1][t]*rT[1][t];
    float r2 = rT[2][t]*rT[2][t], r3 = rT[3][t]*rT[3][t];
    float r4 = rT[4][t]*rT[4][t], r5 = rT[5][t]*rT[5][t];
    float r6 = rT[6][t]*rT[6][t], r7 = rT[7][t]*rT[7][t];
    for (int i = 8; i < 64; i += 8){
      float s0 = rT[i+0][t]*rT[i+0][t]; r0 = r0 + s0;
      float s1 = rT[i+1][t]*rT[i+1][t]; r1 = r1 + s1;
      float s2 = rT[i+2][t]*rT[i+2][t]; r2 = r2 + s2;
      float s3 = rT[i+3][t]*rT[i+3][t]; r3 = r3 + s3;
      float s4 = rT[i+4][t]*rT[i+4][t]; r4 = r4 + s4;
      float s5 = rT[i+5][t]*rT[i+5][t]; r5 = r5 + s5;
      float s6 = rT[i+6][t]*rT[i+6][t]; r6 = r6 + s6;
      float s7 = rT[i+7][t]*rT[i+7][t]; r7 = r7 + s7;
    }
    sR[t] = ((r0 + r1) + (r2 + r3)) + ((r4 + r5) + (r6 + r7));
  }
  __syncthreads();

  int rg = t >> 4;   // owns rows rg*8..rg*8+7
  int cg = t & 15;   // owns codes cg*4..cg*4+3 within tile
  float sRl[8];
#pragma unroll
  for (int k2 = 0; k2 < 8; k2++) sRl[k2] = sR[rg*8 + k2];

  float best[8]; int bidx[8];
#pragma unroll
  for (int k2 = 0; k2 < 8; k2++){ best[k2] = 3.0e38f; bidx[k2] = 0; }

  for (int tile = 0; tile < NT; tile++){
    int vt = v0 + tile*TV;
    for (int e = t; e < (64*TV)/4; e += 256){
      int c = e >> 4;
      int v4 = e & 15;
      *(float4*)&eL[c][v4*4] = *(const float4*)&e32T[c*VV + vt + v4*4];
    }
    __syncthreads();

    float acc[8][4];
#pragma unroll
    for (int a = 0; a < 8; a++)
#pragma unroll
      for (int k = 0; k < 4; k++) acc[a][k] = 0.0f;

    for (int c = 0; c < 64; c++){
      float4 ra = *(const float4*)&rT[c][rg*8];
      float4 rb = *(const float4*)&rT[c][rg*8 + 4];
      float4 ea = *(const float4*)&eL[c][cg*4];
      float rr[8] = {ra.x, ra.y, ra.z, ra.w, rb.x, rb.y, rb.z, rb.w};
      float ee[4] = {ea.x, ea.y, ea.z, ea.w};
#pragma unroll
      for (int a = 0; a < 8; a++)
#pragma unroll
        for (int k = 0; k < 4; k++)
          acc[a][k] = fmaf(ee[k], rr[a], acc[a][k]);   // c-ascending, single accumulator
    }

    int vloc = tile*TV + cg*4;
#pragma unroll
    for (int k2 = 0; k2 < 8; k2++){
#pragma unroll
      for (int k = 0; k < 4; k++){
        float es = esL[vloc + k];
        float t1 = sRl[k2] + es;                        // fl(R + e_sq)
        float d  = t1 - 2.0f*acc[k2][k];                // fl(t1 - 2*dot)
        if (d < best[k2]) { best[k2] = d; bidx[k2] = vt + cg*4 + k; }
      }
    }
    __syncthreads();
  }

  // reduce per row over the 16 cg lanes of group rg (first-min: smaller v on tie)
#pragma unroll
  for (int k2 = 0; k2 < 8; k2++){
    float v = best[k2]; int ix = bidx[k2];
    for (int off = 8; off; off >>= 1){
      float ov = __shfl_down(v, off, 16);
      int   oi = __shfl_down(ix, off, 16);
      if (ov < v || (ov == v && oi < ix)) { v = ov; ix = oi; }
    }
    if (cg == 0){
      int n = n0 + rg*8 + k2;
      bestW[n*NSPLIT + split] = v;
      idxW [n*NSPLIT + split] = ix;
    }
  }
}

// ---------------- fused split-reduce + upsample/gather + Phi + next-scale downsample ----------------

template<int PN, int PN2, int NSPLIT, bool LAST>
__global__ __launch_bounds__(256) void fused_phi(
    const float* __restrict__ emb,
    const float* __restrict__ bestW, const int* __restrict__ idxW,
    const float* __restrict__ Mup, const float* __restrict__ wP,
    const float* __restrict__ bias, const float* __restrict__ f,
    float* fhat, float* frest, float* levels_out, float* final_out,
    float* rest_next, const float* __restrict__ Mdown_next,
    double* partial, int si)
{
#pragma clang fp contract(off)
  __shared__ float huP[64][36];   // [ci][1+h], zero borders at 0 and 33
  __shared__ union { float hE[24*64]; float frL[64*33]; } u;   // phase-disjoint
  __shared__ float wL[64*196];    // [co][ci*3+kh], float4-clean stride
  __shared__ float mUp[32*25];    // [o][p], stride PN+1 (<=25)
  __shared__ float mDn[32*33];    // [p][h], stride 33
  __shared__ int idxL[32];
  __shared__ double red[4];
  int b = blockIdx.x, t = threadIdx.x;

  // fold of argmin_reduce: cross-split first-min (splits ascending, strict <)
  if (t < PN){
    int base = (b*PN + t)*NSPLIT;
    float v = bestW[base]; int ix = idxW[base];
#pragma unroll
    for (int s = 1; s < NSPLIT; s++){
      float ov = bestW[base + s];
      if (ov < v) { v = ov; ix = idxW[base + s]; }
    }
    idxL[t] = ix;
  }
  if (t < 64){ huP[t][0] = 0.0f; huP[t][33] = 0.0f; huP[t][34] = 0.0f; huP[t][35] = 0.0f; }
  // coalesced float4 staging of packed weights (12544 floats = 3136 float4)
  for (int e = t; e < 3136; e += 256)
    *(float4*)&wL[e*4] = *(const float4*)&wP[e*4];
  if (PN2 > 0){
    for (int e = t; e < PN2*32; e += 256){
      int p = e >> 5, h = e & 31;
      mDn[p*33 + h] = Mdown_next[e];
    }
  }
  if (!LAST){
    for (int e = t; e < 32*PN; e += 256){
      int o = e / PN, p = e - o*PN;
      mUp[o*(PN+1) + p] = Mup[e];
    }
  }
  __syncthreads();

  if (!LAST){
    for (int e = t; e < PN*64; e += 256){
      int p = e >> 6, c = e & 63;
      u.hE[p*64 + c] = emb[idxL[p]*64 + c];
    }
    __syncthreads();
    for (int e = t; e < 2048; e += 256){
      int c = e >> 5, o = e & 31;
      const float* mr = &mUp[o*(PN+1)];
      float s = 0.0f;
#pragma unroll
      for (int p = 0; p < PN; p++){ float pr = mr[p]*u.hE[p*64 + c]; s = s + pr; }
      huP[c][1 + o] = s;
    }
  } else {
    for (int e = t; e < 2048; e += 256){
      int h = e >> 6, c = e & 63;
      huP[c][1 + h] = emb[idxL[h]*64 + c];
    }
  }
  __syncthreads();   // hE dead after this point

  // conv3 along H; vectorized LDS reads (aligned: huP row base 144B, h0 multiple of 8)
  int co = t >> 2, h0 = (t & 3) * 8;
  float y[8];
#pragma unroll
  for (int uu = 0; uu < 8; uu++) y[uu] = 0.0f;
  for (int ci4 = 0; ci4 < 64; ci4 += 4){
    float4 wa = *(const float4*)&wL[co*196 + ci4*3];
    float4 wb = *(const float4*)&wL[co*196 + ci4*3 + 4];
    float4 wc = *(const float4*)&wL[co*196 + ci4*3 + 8];
    float wv[12] = {wa.x,wa.y,wa.z,wa.w, wb.x,wb.y,wb.z,wb.w, wc.x,wc.y,wc.z,wc.w};
#pragma unroll
    for (int q = 0; q < 4; q++){
      int ci = ci4 + q;
      float4 xa = *(const float4*)&huP[ci][h0];
      float4 xb = *(const float4*)&huP[ci][h0 + 4];
      float2 xc = *(const float2*)&huP[ci][h0 + 8];
      float x[10] = {xa.x,xa.y,xa.z,xa.w, xb.x,xb.y,xb.z,xb.w, xc.x,xc.y};
      float w0 = wv[q*3], w1 = wv[q*3+1], w2 = wv[q*3+2];
#pragma unroll
      for (int uu = 0; uu < 8; uu++){
        y[uu] = fmaf(w0, x[uu],   y[uu]);
        y[uu] = fmaf(w1, x[uu+1], y[uu]);
        y[uu] = fmaf(w2, x[uu+2], y[uu]);
      }
    }
  }

  float bb = bias[co];
  double lsum = 0.0;
  int base = b*2048 + co*32 + h0;
#pragma unroll
  for (int uu = 0; uu < 8; uu++){
    float yv = y[uu] + bb;                           // conv + bias (after)
    float hp = 0.5f*huP[co][1 + h0 + uu] + 0.5f*yv;  // h*(1-r) + y*r, r=0.5
    float fh = fhat[base+uu] + hp;
    fhat[base+uu] = fh;
    float fr = frest[base+uu] - hp;
    frest[base+uu] = fr;
    u.frL[co*33 + h0 + uu] = fr;
    float fv = f[base+uu];
    float dv = fh - fv;
    lsum += (double)dv*(double)dv;
    levels_out[base+uu] = fh;
    if (LAST) final_out[base+uu] = dv + fv;    // straight-through: fl(fl(fh-f)+f)
  }
  for (int off = 32; off; off >>= 1) lsum += __shfl_down(lsum, off);
  if ((t & 63) == 0) red[t >> 6] = lsum;
  __syncthreads();

  if (PN2 > 0){
    for (int e = t; e < 64*PN2; e += 256){
      int c = e / PN2, p = e - c*PN2;
      const float* mr = &mDn[p*33];
      float s = 0.0f;
#pragma unroll
      for (int h = 0; h < 32; h++){ float pr = mr[h]*u.frL[c*33 + h]; s = s + pr; }
      rest_next[(b*64 + c)*PN2 + p] = s;
    }
  }
  if (t == 0) atomicAdd(&partial[si], red[0] + red[1] + red[2] + red[3]);
}

__global__ void finalize(const double* partial, float* out_loss){
#pragma clang fp contract(off)
  float L = 0.0f;
  for (int si = 0; si < 10; si++){
    float m = (float)(partial[si] / (double)NEL);
    float t1 = 0.25f * m;
    L = L + t1;
    L = L + m;
  }
  L = L / 10.0f;
  *out_loss = L;
}

// ---------------- host ----------------

struct Ptrs {
  const float *f, *emb;
  float *e32T, *e_sq, *frest, *fhat, *rest, *Mdown, *Mup, *wPack, *bestW;
  int *idxW;
  double *partial;
  float *out0, *out_levels;
  const float *phi_b;
};

template<int PN, int PN2, int NSPLIT, bool LAST>
static void run_scale(const Ptrs& P, int si, int pi, int mup_off, int mdn_off,
                      hipStream_t stream){
  constexpr int N = BB*PN;
  dim3 ag(N/RT, NSPLIT);
  const float* restp = LAST ? P.f : P.rest;
  argmin_k<PN, NSPLIT><<<ag, 256, 0, stream>>>(restp, P.e32T, P.e_sq, P.bestW, P.idxW);
  fused_phi<PN, PN2, NSPLIT, LAST><<<BB, 256, 0, stream>>>(
      P.emb, P.bestW, P.idxW, P.Mup + mup_off,
      P.wPack + (size_t)pi*64*196, P.phi_b + (size_t)pi*CC,
      P.f, P.fhat, P.frest, P.out_levels + (size_t)si*NEL, P.out0,
      P.rest, P.Mdown + mdn_off, P.partial, si);
}

extern "C" void kernel_launch(void* const* d_in, const int* in_sizes, int n_in,
                              void* d_out, int out_size, void* d_ws, size_t ws_size,
                              hipStream_t stream) {
  const float* f     = (const float*)d_in[0];
  const float* emb   = (const float*)d_in[1];
  const float* phi_w = (const float*)d_in[2];
  const float* phi_b = (const float*)d_in[3];
  float* out0       = (float*)d_out;
  float* out_loss   = out0 + NEL;
  float* out_levels = out0 + NEL + 1;

  double* partial = (double*)d_ws;             // 16
  float*  e32T    = (float*)(partial + 16);    // 262144
  float*  e_sq    = e32T + 262144;             // 4096
  float*  frest   = e_sq + 4096;               // NEL
  float*  fhat    = frest + NEL;               // NEL
  float*  rest    = fhat + NEL;                // NEL (max)
  float*  Mdown   = rest + NEL;                // 3584
  float*  Mup     = Mdown + 3584;              // 3584
  float*  wPack   = Mup + 3584;                // 50176
  float*  bestW   = wPack + 50176;             // 262144
  int*    idxW    = (int*)(bestW + 262144);    // 262144

  // pi table: exact IEEE-fp64 mirror of np.linspace + argmin(|TICKS - si/9|)
  double q = 1.0/3.0; q = q/4.0;
  double start = q;
  double stop  = 1.0 - q;
  double delta = stop - start;
  double step  = delta/3.0;
  double ticks[4];
  ticks[0] = start;
  ticks[1] = step + start;
  { double t2 = 2.0*step; ticks[2] = t2 + start; }
  ticks[3] = stop;
  int pi_tab[10];
  for (int si = 0; si < 10; si++){
    double x = (double)si / 9.0;
    int bi = 0; double bd = fabs(ticks[0] - x);
    for (int i2 = 1; i2 < 4; i2++){
      double dd = fabs(ticks[i2] - x);
      if (dd < bd) { bd = dd; bi = i2; }
    }
    pi_tab[si] = bi;
  }

  static const int pref[10] = {0,1,3,6,10,16,25,38,56,80};

  gen_setup<<<1, 64, 0, stream>>>(Mdown, Mup, partial);
  pack_w<<<64, 256, 0, stream>>>(phi_w, wPack);
  prep_emb<<<16, 256, 0, stream>>>(emb, e32T, e_sq);
  init_k<<<BB, 256, 0, stream>>>(f, frest, fhat, rest, Mdown /* scale0: [1][32] */);

  Ptrs P = {f, emb, e32T, e_sq, frest, fhat, rest, Mdown, Mup, wPack, bestW,
            idxW, partial, out0, out_levels, phi_b};

  // scale 9 quantizes f itself (reference: rest = f), so si=8 needs no downsample (PN2=0)
  run_scale< 1,  2, 32, false>(P, 0, pi_tab[0], pref[0]*32, pref[1]*32, stream);
  run_scale< 2,  3, 32, false>(P, 1, pi_tab[1], pref[1]*32, pref[2]*32, stream);
  run_scale< 3,  4, 32, false>(P, 2, pi_tab[2], pref[2]*32, pref[3]*32, stream);
  run_scale< 4,  6, 32, false>(P, 3, pi_tab[3], pref[3]*32, pref[4]*32, stream);
  run_scale< 6,  9, 16, false>(P, 4, pi_tab[4], pref[4]*32, pref[5]*32, stream);
  run_scale< 9, 13, 16, false>(P, 5, pi_tab[5], pref[5]*32, pref[6]*32, stream);
  run_scale<13, 18,  8, false>(P, 6, pi_tab[6], pref[6]*32, pref[7]*32, stream);
  run_scale<18, 24,  8, false>(P, 7, pi_tab[7], pref[7]*32, pref[8]*32, stream);
  run_scale<24,  0,  8, false>(P, 8, pi_tab[8], pref[8]*32, 0,          stream);
  run_scale<32,  0,  8, true >(P, 9, pi_tab[9], pref[9]*32, 0,          stream);

  finalize<<<1, 1, 0, stream>>>(partial, out_loss);
}